// Round 9
// baseline (115.849 us; speedup 1.0000x reference)
//
#include <hip/hip_runtime.h>

// B=32, C=8, L=2048, K=512, S=64, W=1985
// out[b,0,q] = max(0, max_w sum_c dot(xw_n[b,c,w,:], sn_n[c,q,:]) / 8)

#define B_ 32
#define C_ 8
#define L_ 2048
#define K_ 512
#define S_ 64
#define W_ 1985
#define TW 128                        // windows per block tile

typedef _Float16 f16x8 __attribute__((ext_vector_type(8)));
typedef _Float16 f16x8u __attribute__((ext_vector_type(8), aligned(4)));
typedef float f32x16 __attribute__((ext_vector_type(16)));

// ---- prologue ----
// blocks 0..127:   pack shapelets in 32x32x16 B-frag layout
// blocks 128..383: per-row f16 x copies (xh0[p]=x[p], xh1[p]=x[p+1]),
//                  f16 window inv-norms, zero out
__global__ __launch_bounds__(256)
void prep_k(const float* __restrict__ x, const float* __restrict__ sh,
            _Float16* __restrict__ Bp, _Float16* __restrict__ xh0,
            _Float16* __restrict__ xh1, _Float16* __restrict__ invh,
            float* __restrict__ out) {
    __shared__ float xr[L_];             // norm blocks only
    const int tid = threadIdx.x;
    const int blk = blockIdx.x;

    if (blk < 128) {
        const int sb   = blk * 4 + (tid >> 6);   // 0..511 = c(8) x kq(4) x nt(16)
        const int c    = sb >> 6;
        const int kq   = (sb >> 4) & 3;
        const int nt   = sb & 15;
        const int lane = tid & 63;
        const int half = lane >> 5;
        const int q    = nt * 32 + (lane & 31);

        const float4* sp = (const float4*)(sh + (size_t)(c * K_ + q) * S_);
        float ss = 0.f;
        #pragma unroll
        for (int i = 0; i < 8; ++i) {
            float4 v = sp[half * 8 + i];
            ss += v.x * v.x + v.y * v.y + v.z * v.z + v.w * v.w;
        }
        ss += __shfl_xor(ss, 32);
        float inv = 1.f / fmaxf(sqrtf(ss), 1e-8f);

        float4 u0 = sp[kq * 4 + half * 2];
        float4 u1 = sp[kq * 4 + half * 2 + 1];
        f16x8 o;
        o[0] = (_Float16)(u0.x * inv); o[1] = (_Float16)(u0.y * inv);
        o[2] = (_Float16)(u0.z * inv); o[3] = (_Float16)(u0.w * inv);
        o[4] = (_Float16)(u1.x * inv); o[5] = (_Float16)(u1.y * inv);
        o[6] = (_Float16)(u1.z * inv); o[7] = (_Float16)(u1.w * inv);
        ((f16x8*)Bp)[((c * 4 + kq) * 16 + nt) * 64 + lane] = o;
    } else {
        const int r = blk - 128;             // row = b*8 + c, 0..255
        const float* xp = x + (size_t)r * L_;
        for (int i = tid; i < L_ / 4; i += 256)
            ((float4*)xr)[i] = ((const float4*)xp)[i];
        __syncthreads();

        // f16 dual copies (one f16x8 chunk per thread)
        {
            const int i = tid * 8;
            f16x8 a, bsh;
            #pragma unroll
            for (int j = 0; j < 8; ++j) {
                a[j]   = (_Float16)xr[i + j];
                int n  = i + j + 1;
                bsh[j] = (_Float16)(n < L_ ? xr[n] : 0.f);
            }
            *(f16x8*)(xh0 + (size_t)r * L_ + i) = a;
            *(f16x8*)(xh1 + (size_t)r * L_ + i) = bsh;
        }

        // window inverse norms via sliding sum -> f16
        _Float16* ivp = invh + (size_t)r * L_;
        const int w0 = tid * 8;
        float ss = 0.f;
        if (w0 < W_) {
            #pragma unroll
            for (int j = 0; j < S_; ++j) { float v = xr[w0 + j]; ss += v * v; }
        }
        #pragma unroll
        for (int u = 0; u < 8; ++u) {
            int w = w0 + u;
            float o = 0.f;
            if (u > 0 && w < W_)
                ss += xr[w + 63] * xr[w + 63] - xr[w - 1] * xr[w - 1];
            if (w < W_) o = 0.125f / fmaxf(sqrtf(ss), 1e-8f);
            if (w < L_) ivp[w] = (_Float16)o;
        }
        if (r < 64) out[r * 256 + tid] = 0.f;   // zero output
    }
}

// ---- main: barrier-free, 4-waves/SIMD MFMA GEMM + relu + max ----
// grid (16 wt, 4 ng, 32 b) = 2048 blocks, 256 threads = 4 independent waves.
// Wave (mg,nw): 64 windows (mt=2 x 32) x 64 cols (nt=2 x 32).
// A data pre-converted f16 (parity-dual copy -> one 16B load per frag);
// A-build = 4 v_pk_mul_f16 per frag. acc = 2x2 x f32x16 = 64 regs.
__global__ __launch_bounds__(256, 4)
void mcs_k(const _Float16* __restrict__ Bp, const _Float16* __restrict__ xh0,
           const _Float16* __restrict__ xh1, const _Float16* __restrict__ invh,
           float* __restrict__ out) {
    const int wt  = blockIdx.x;
    const int ng  = blockIdx.y;
    const int b   = blockIdx.z;
    const int tid = threadIdx.x;
    const int lane = tid & 63;
    const int wv   = tid >> 6;
    const int mg   = wv >> 1;
    const int nw   = wv & 1;

    const int l31 = lane & 31;
    const int lh  = lane >> 5;
    const int Wb  = wt * TW + mg * 64;
    const int par = l31 & 1;              // fixed per lane -> pointer picked once

    const _Float16* xb  = (par ? xh1 - 1 : xh0) + (size_t)(b * C_) * L_;
    const _Float16* ivb = invh + (size_t)(b * C_) * L_;
    const f16x8* Bq     = (const f16x8*)Bp;
    const int coloff    = (ng * 4 + nw * 2) * 64 + lane;

    f16x8  Bbuf[3][2];        // 24 VGPRs: B frags, 2-step prefetch ring
    f16x8u Abuf[2][2];        // 16 VGPRs: raw f16 A frags, 1-step prefetch
    _Float16 ivr[2][2];       // per-channel row scales, 1-channel prefetch

    auto issueB = [&](int s, int slot) {
        const int c = s >> 2, ks = s & 3;
        const f16x8* bb = Bq + ((c * 4 + ks) * 16) * 64 + coloff;
        Bbuf[slot][0] = bb[0];
        Bbuf[slot][1] = bb[64];
    };
    auto issueA = [&](int s, int slot) {
        const int c = s >> 2, ks = s & 3;
        const _Float16* xr = xb + c * L_;
        #pragma unroll
        for (int mt = 0; mt < 2; ++mt) {
            int p  = Wb + mt * 32 + l31 + ks * 16 + lh * 8;
            int pc = p <= L_ - 8 ? p : L_ - 8;   // only invalid windows clamp
            Abuf[slot][mt] = *(const f16x8u*)(xr + pc);
        }
    };

    // prolog
    ivr[0][0] = ivb[Wb + l31];            // 0 for invalid windows
    ivr[0][1] = ivb[Wb + 32 + l31];
    issueB(0, 0);
    issueA(0, 0);
    issueB(1, 1);

    f32x16 acc[2][2];
    #pragma unroll
    for (int mt = 0; mt < 2; ++mt)
        #pragma unroll
        for (int nt = 0; nt < 2; ++nt)
            #pragma unroll
            for (int r = 0; r < 16; ++r) acc[mt][nt][r] = 0.f;

    #pragma unroll
    for (int s = 0; s < 32; ++s) {
        const int c = s >> 2, ks = s & 3;
        if (s + 2 < 32) issueB(s + 2, (s + 2) % 3);
        if (s + 1 < 32) issueA(s + 1, (s + 1) & 1);
        if (ks == 0 && c + 1 < C_) {
            const _Float16* ivn = ivb + (c + 1) * L_;
            ivr[(c + 1) & 1][0] = ivn[Wb + l31];
            ivr[(c + 1) & 1][1] = ivn[Wb + 32 + l31];
        }
        // A-build: packed f16 multiply by row scale
        f16x8 af0 = (f16x8)Abuf[s & 1][0] * ivr[c & 1][0];
        f16x8 af1 = (f16x8)Abuf[s & 1][1] * ivr[c & 1][1];

        #pragma unroll
        for (int nt = 0; nt < 2; ++nt) {
            acc[0][nt] = __builtin_amdgcn_mfma_f32_32x32x16_f16(
                af0, Bbuf[s % 3][nt], acc[0][nt], 0, 0, 0);
            acc[1][nt] = __builtin_amdgcn_mfma_f32_32x32x16_f16(
                af1, Bbuf[s % 3][nt], acc[1][nt], 0, 0, 0);
        }
    }

    // epilogue: relu + max over windows (invalid windows exactly 0).
    // 32x32 C/D: col = lane&31; lane and lane^32 cover the same col.
    #pragma unroll
    for (int nt = 0; nt < 2; ++nt) {
        float m = 0.f;
        #pragma unroll
        for (int mt = 0; mt < 2; ++mt)
            #pragma unroll
            for (int r = 0; r < 16; ++r)
                m = fmaxf(m, acc[mt][nt][r]);
        m = fmaxf(m, __shfl_xor(m, 32));
        if (lane < 32)
            atomicMax((unsigned int*)(out + b * K_ + ng * 128 + nw * 64 + nt * 32 + l31),
                      __float_as_uint(m));
    }
}

extern "C" void kernel_launch(void* const* d_in, const int* in_sizes, int n_in,
                              void* d_out, int out_size, void* d_ws, size_t ws_size,
                              hipStream_t stream) {
    const float* x  = (const float*)d_in[0];   // (32, 8, 2048) fp32
    const float* sh = (const float*)d_in[1];   // (8, 512, 64) fp32
    float* out = (float*)d_out;                // (32, 1, 512) fp32

    char* ws = (char*)d_ws;
    _Float16* Bp   = (_Float16*)ws;                       // 512 KB
    _Float16* xh0  = (_Float16*)(ws + (512 << 10));       // 1 MB
    _Float16* xh1  = (_Float16*)(ws + (512 << 10) + (1 << 20));   // 1 MB
    _Float16* invh = (_Float16*)(ws + (512 << 10) + (2 << 20));   // 1 MB

    prep_k<<<dim3(384), dim3(256), 0, stream>>>(x, sh, Bp, xh0, xh1, invh, out);
    mcs_k<<<dim3(16, 4, B_), dim3(256), 0, stream>>>(Bp, xh0, xh1, invh, out);
}